// Round 2
// baseline (1022.647 us; speedup 1.0000x reference)
//
#include <hip/hip_runtime.h>
#include <stdint.h>

typedef short bf8 __attribute__((ext_vector_type(8)));   // 8 bf16 in 4 VGPR
typedef short s4v __attribute__((ext_vector_type(4)));
typedef float f32x4 __attribute__((ext_vector_type(4)));

__device__ __forceinline__ short f2bf(float f){
  union { float f; unsigned u; } c; c.f = f;
  unsigned r = (c.u + 0x7fffu + ((c.u >> 16) & 1u)) >> 16;
  return (short)r;
}
__device__ __forceinline__ float bf2f(short s){
  union { unsigned u; float f; } c; c.u = ((unsigned)(unsigned short)s) << 16;
  return c.f;
}
__device__ __forceinline__ void gload16(const void* g, void* l){
  __builtin_amdgcn_global_load_lds((const __attribute__((address_space(1))) uint32_t*)g,
                                   (__attribute__((address_space(3))) uint32_t*)l, 16, 0, 0);
}
// Fast erf: Abramowitz-Stegun 7.1.26 rational approx, |err| <= 1.5e-7 (<< bf16 step).
// Branchless: ~14 VALU inst vs ~100+ for libm erff with divergent paths.
__device__ __forceinline__ float fast_erf(float x){
  const float s = fabsf(x);
  const float t = __builtin_amdgcn_rcpf(fmaf(0.3275911f, s, 1.0f));
  float p = fmaf(1.061405429f, t, -1.453152027f);
  p = fmaf(p, t, 1.421413741f);
  p = fmaf(p, t, -0.284496736f);
  p = fmaf(p, t, 0.254829592f);
  p = p * t;
  const float e = __expf(-s * s);          // native v_exp
  return copysignf(fmaf(-p, e, 1.0f), x);
}
__device__ __forceinline__ float act_gelu(float x){
  return 0.5f * x * (1.0f + fast_erf(x * 0.70710678118654752f));
}
// softplus(x) = max(x,0) + log(1+exp(-|x|)): branchless, native v_exp/v_log.
__device__ __forceinline__ float act_softplus(float x){
  const float e = __expf(-fabsf(x));
  return fmaxf(x, 0.0f) + __logf(1.0f + e);
}

// ---------------- instance-norm stats: one block per (b,c) row ----------------
__global__ __launch_bounds__(256) void k_stats(const float* __restrict__ x,
                                               float* __restrict__ mu, float* __restrict__ rsig){
  const int row = blockIdx.x;                 // 0..2047
  const float4* xr = (const float4*)(x + (size_t)row * 16384);
  float s1 = 0.f, s2 = 0.f;
  for (int i = threadIdx.x; i < 4096; i += 256){
    float4 v = xr[i];
    s1 += v.x + v.y + v.z + v.w;
    s2 += v.x*v.x + v.y*v.y + v.z*v.z + v.w*v.w;
  }
  __shared__ float a1[256], a2[256];
  a1[threadIdx.x] = s1; a2[threadIdx.x] = s2; __syncthreads();
  for (int s = 128; s > 0; s >>= 1){
    if (threadIdx.x < s){ a1[threadIdx.x] += a1[threadIdx.x+s]; a2[threadIdx.x] += a2[threadIdx.x+s]; }
    __syncthreads();
  }
  if (threadIdx.x == 0){
    float m = a1[0] * (1.0f/16384.0f);
    float v = a2[0] * (1.0f/16384.0f) - m*m;
    mu[row] = m; rsig[row] = rsqrtf(v + 1e-5f);
  }
}

// ------------- normalize + transpose: x (B,C,N) f32 -> xn (B,N,C) bf16 -------------
__global__ __launch_bounds__(256) void k_normt(const float* __restrict__ x, const float* __restrict__ mu,
                                               const float* __restrict__ rsig, short* __restrict__ xn){
  const int n0 = blockIdx.x * 64, c0 = blockIdx.y * 64, b = blockIdx.z;
  __shared__ short lt[64][68];                 // pad 68 -> 136B rows (8B aligned, ~2-way)
  const int t = threadIdx.x;
  const int nj = (t & 15) * 4, cb = t >> 4;
#pragma unroll
  for (int it = 0; it < 4; ++it){
    const int ci = cb + it * 16;
    const int row = b * 256 + c0 + ci;
    const float m = mu[row], rs = rsig[row];
    float4 v = *(const float4*)(x + (size_t)row * 16384 + n0 + nj);
    s4v o;
    o[0] = f2bf((v.x - m) * rs); o[1] = f2bf((v.y - m) * rs);
    o[2] = f2bf((v.z - m) * rs); o[3] = f2bf((v.w - m) * rs);
    *(s4v*)(&lt[ci][nj]) = o;
  }
  __syncthreads();
#pragma unroll
  for (int p = 0; p < 2; ++p){
    const int q = p * 256 + t;
    const int nl = q >> 3, c8 = (q & 7) * 8;
    bf8 o;
#pragma unroll
    for (int j = 0; j < 8; ++j) o[j] = lt[c8 + j][nl];
    *(bf8*)(xn + ((size_t)(b * 16384 + n0 + nl)) * 256 + c0 + c8) = o;
  }
}

// ------------- fp32->bf16 weight conversion (7 matrices of 256x256) -------------
__global__ __launch_bounds__(256) void k_wconv(const float* w0, const float* w1, const float* w2,
                                               const float* w3, const float* w4, const float* w5,
                                               const float* w6, short* __restrict__ wb){
  const int gid = blockIdx.x * 256 + threadIdx.x;  // float4 chunks, 0..114687
  const int mat = gid >> 14, r4 = gid & 16383;
  const float* srcs[7] = {w0, w1, w2, w3, w4, w5, w6};
  float4 v = *(const float4*)(srcs[mat] + (size_t)r4 * 4);
  s4v o; o[0] = f2bf(v.x); o[1] = f2bf(v.y); o[2] = f2bf(v.z); o[3] = f2bf(v.w);
  *(s4v*)(wb + (size_t)mat * 65536 + r4 * 4) = o;
}

// ---------------- GEMM: out[m][o] = act(sum_c A[m][c] * W[o][c] + bias[o]) ----------------
// A: (131072,256) bf16 row-major; W: (256,256) bf16 row-major. 128x256 tile, 4 waves x (64x128).
// K-slot swizzle: XOR with ((row>>1)&3) — row stride 64B has bank period 2 rows, so this
// gives exactly 2-way (free) instead of 4-way with (row&3).
// OUTMODE 0: bf16 (M,256), chunked 32-row LDS repack (16.9KB) -> 40.5KB total, 3 blocks/CU.
// OUTMODE 1: fp32 transposed (B,256,16384) direct float4.
template<int ACT, int OUTMODE>
__global__ __launch_bounds__(256, OUTMODE == 0 ? 3 : 4)
void k_gemm(const short* __restrict__ A, const short* __restrict__ W,
            const float* __restrict__ bias, void* __restrict__ outv){
  __shared__ short sm[12288];
  short* sA = sm;            // [128][32] bf16, 64B rows
  short* sB = sm + 4096;     // [256][32] bf16
  const int t = threadIdx.x, l = t & 63, w = t >> 6;
  const int wr = w >> 1, wc = w & 1;
  const int lm = l & 15, lk = l >> 4;
  const size_t m0 = (size_t)blockIdx.x * 128;
  const int swz = ((lk ^ ((lm >> 1) & 3)) << 4);   // byte offset of swizzled 16B k-slot
  f32x4 acc[4][8] = {};

  for (int ks = 0; ks < 8; ++ks){
    const int k0 = ks * 32;
#pragma unroll
    for (int p = 0; p < 2; ++p){
      const int q = p * 256 + t, r = q >> 2, kc = q & 3;
      gload16(A + (m0 + r) * 256 + k0 + ((kc ^ ((r >> 1) & 3)) << 3),
              (char*)sA + (p * 256 + w * 64) * 16);
    }
#pragma unroll
    for (int p = 0; p < 4; ++p){
      const int q = p * 256 + t, r = q >> 2, kc = q & 3;
      gload16(W + (size_t)r * 256 + k0 + ((kc ^ ((r >> 1) & 3)) << 3),
              (char*)sB + (p * 256 + w * 64) * 16);
    }
    __syncthreads();
    bf8 af[4], bfv[8];
#pragma unroll
    for (int mi = 0; mi < 4; ++mi)
      af[mi] = *(const bf8*)((const char*)sA + (wr * 64 + mi * 16 + lm) * 64 + swz);
#pragma unroll
    for (int ni = 0; ni < 8; ++ni)
      bfv[ni] = *(const bf8*)((const char*)sB + (wc * 128 + ni * 16 + lm) * 64 + swz);
#pragma unroll
    for (int mi = 0; mi < 4; ++mi)
#pragma unroll
      for (int ni = 0; ni < 8; ++ni)
        acc[mi][ni] = __builtin_amdgcn_mfma_f32_16x16x32_bf16(af[mi], bfv[ni], acc[mi][ni], 0, 0, 0);
    __syncthreads();
  }

  if constexpr (OUTMODE == 0){
    __shared__ short rp[32 * 264];     // one 32-row chunk per mi pass
    short* outp = (short*)outv;
#pragma unroll
    for (int mi = 0; mi < 4; ++mi){
      __syncthreads();                 // previous pass's copy-out done before overwrite
      const int rloc = wr * 16 + lk * 4;
#pragma unroll
      for (int ni = 0; ni < 8; ++ni){
        const int o = wc * 128 + ni * 16 + lm;
        const float bi = bias[o];
#pragma unroll
        for (int j = 0; j < 4; ++j){
          float v = acc[mi][ni][j] + bi;
          if (ACT == 1) v = act_gelu(v);
          else if (ACT == 2) v = act_softplus(v);
          rp[(rloc + j) * 264 + o] = f2bf(v);
        }
      }
      __syncthreads();
#pragma unroll
      for (int it = 0; it < 4; ++it){
        const int q = it * 256 + t, rr = q >> 5, c = q & 31;
        const int gr = (rr >> 4) * 64 + mi * 16 + (rr & 15);
        *(bf8*)(outp + (m0 + gr) * 256 + c * 8) = *(const bf8*)(rp + rr * 264 + c * 8);
      }
    }
  } else {
    float* outp = (float*)outv;
    const size_t b = m0 >> 14;
    const int nb = (int)(m0 & 16383);
#pragma unroll
    for (int mi = 0; mi < 4; ++mi){
      const int np = nb + wr * 64 + mi * 16 + lk * 4;   // 4 consecutive pixels via f32x4 lanes
#pragma unroll
      for (int ni = 0; ni < 8; ++ni){
        const int o = wc * 128 + ni * 16 + lm;
        const float bi = bias[o];
        float4 v;
        v.x = acc[mi][ni][0] + bi; v.y = acc[mi][ni][1] + bi;
        v.z = acc[mi][ni][2] + bi; v.w = acc[mi][ni][3] + bi;
        *(float4*)(outp + ((b * 256 + o) * 16384 + np)) = v;
      }
    }
  }
}

// ---------- kv partials: kv[c][d] = sum_n K[c][n]*V[d][n], n split 8-way; + ksum ----------
__global__ __launch_bounds__(256) void k_kv(const short* __restrict__ kg, const short* __restrict__ vg,
                                            float* __restrict__ kvpart, float* __restrict__ kspart){
  const int s = blockIdx.x, h = blockIdx.y, b = blockIdx.z;
  __shared__ short sk[64 * 72], sv[64 * 72];   // [c][n] bf16, pad 72 -> 144B rows (16B aligned)
  __shared__ float pl[256][8];
  const int t = threadIdx.x, l = t & 63, w = t >> 6;
  const int lm = l & 15, lk = l >> 4;
  float ksp[8];
#pragma unroll
  for (int j = 0; j < 8; ++j) ksp[j] = 0.f;
  f32x4 acc[4] = {};
  const size_t rowbase = ((size_t)b * 16384 + s * 2048) * 256 + h * 64;

  for (int tt = 0; tt < 32; ++tt){
    __syncthreads();
#pragma unroll
    for (int p = 0; p < 2; ++p){
      const int q = p * 256 + t;
      const int nl = q >> 3, c8 = (q & 7) * 8;
      bf8 kvv = *(const bf8*)(kg + rowbase + (size_t)(tt * 64 + nl) * 256 + c8);
      bf8 vvv = *(const bf8*)(vg + rowbase + (size_t)(tt * 64 + nl) * 256 + c8);
#pragma unroll
      for (int j = 0; j < 8; ++j){
        sk[(c8 + j) * 72 + nl] = kvv[j];
        sv[(c8 + j) * 72 + nl] = vvv[j];
        ksp[j] += bf2f(kvv[j]);
      }
    }
    __syncthreads();
#pragma unroll
    for (int ks = 0; ks < 2; ++ks){
      bf8 ak = *(const bf8*)((const char*)sk + (w * 16 + lm) * 144 + ks * 64 + lk * 16);
#pragma unroll
      for (int ni = 0; ni < 4; ++ni){
        bf8 bv = *(const bf8*)((const char*)sv + (ni * 16 + lm) * 144 + ks * 64 + lk * 16);
        acc[ni] = __builtin_amdgcn_mfma_f32_16x16x32_bf16(ak, bv, acc[ni], 0, 0, 0);
      }
    }
  }
#pragma unroll
  for (int j = 0; j < 8; ++j) pl[t][j] = ksp[j];
  __syncthreads();
  const size_t slot = (size_t)(b * 4 + h) * 8 + s;
  if (t < 64){
    float sum = 0.f;
    const int g8 = t >> 3, j = t & 7;
    for (int m = 0; m < 32; ++m) sum += pl[m * 8 + g8][j];
    kspart[slot * 64 + t] = sum;
  }
  float* kvp = kvpart + slot * 4096;
#pragma unroll
  for (int ni = 0; ni < 4; ++ni)
#pragma unroll
    for (int j = 0; j < 4; ++j){
      const int c = w * 16 + lk * 4 + j, d = ni * 16 + lm;
      kvp[c * 64 + d] = acc[ni][j];
    }
}

// ---------- reduce partials -> kvT_s (b,h,d,c) bf16 (scale folded) + ksum_s fp32 ----------
__global__ __launch_bounds__(256) void k_kvred(const float* __restrict__ kvpart, const float* __restrict__ kspart,
                                               short* __restrict__ kvT, float* __restrict__ ksum_s){
  const int gid = blockIdx.x * 256 + threadIdx.x;   // 0..16383
#pragma unroll
  for (int i = 0; i < 8; ++i){
    const int o = gid * 8 + i;                      // output index into kvT
    const int bh = o >> 12, rem = o & 4095, d = rem >> 6, c = rem & 63;
    float sum = 0.f;
#pragma unroll
    for (int s = 0; s < 8; ++s) sum += kvpart[((size_t)bh * 8 + s) * 4096 + c * 64 + d];
    kvT[o] = f2bf(sum * 0.125f);
  }
  if (gid < 2048){
    float sum = 0.f;
#pragma unroll
    for (int s = 0; s < 8; ++s) sum += kspart[((size_t)(gid >> 6) * 8 + s) * 64 + (gid & 63)];
    ksum_s[gid] = sum * 0.125f;
  }
}

// ---------- attention finalize: y = ((q^T kv)*scale + v) * z * g, per 64-pixel tile ----------
__global__ __launch_bounds__(256, 2) void k_attn(const short* __restrict__ qg, const short* __restrict__ vg,
                                                 const short* __restrict__ gg, const short* __restrict__ kvT,
                                                 const float* __restrict__ ksum_s, short* __restrict__ y){
  const int n0 = blockIdx.x * 64, b = blockIdx.y;
  __shared__ short sq[64 * 264];     // q tile then reused for y tile; 528B rows
  __shared__ short skv[256 * 72];    // kvT (h*64+d, c), 144B rows
  __shared__ float sz[256];
  __shared__ float sks[256];
  const int t = threadIdx.x, l = t & 63, w = t >> 6;
  const int lm = l & 15, lk = l >> 4;
  const size_t mrow = (size_t)b * 16384 + n0;

#pragma unroll
  for (int it = 0; it < 8; ++it){
    const int q = it * 256 + t, p = q >> 5, c16 = (q & 31) * 8;
    *(bf8*)((char*)sq + p * 528 + c16 * 2) = *(const bf8*)(qg + (mrow + p) * 256 + c16);
  }
  const short* kvb = kvT + (size_t)b * 16384;
#pragma unroll
  for (int it = 0; it < 8; ++it){
    const int q = it * 256 + t, r = q >> 3, c8 = (q & 7) * 8;
    *(bf8*)((char*)skv + r * 144 + c8 * 2) = *(const bf8*)(kvb + r * 64 + c8);
  }
  sks[t] = ksum_s[b * 256 + t];
  __syncthreads();

  {  // z = 1/(q . ksum_s + n) — per pixel p, head h; wave-local columns
    const int p = t & 63, h = t >> 6;
    float dot = 0.f;
#pragma unroll
    for (int cc = 0; cc < 8; ++cc){
      bf8 qv = *(const bf8*)((const char*)sq + p * 528 + (h * 64 + cc * 8) * 2);
#pragma unroll
      for (int j = 0; j < 8; ++j) dot += bf2f(qv[j]) * sks[h * 64 + cc * 8 + j];
    }
    sz[h * 64 + p] = 1.0f / (dot + 16384.0f);
  }

  const int h = w;                    // wave == head
  f32x4 acc[4][4] = {};
#pragma unroll
  for (int ks = 0; ks < 2; ++ks){
    bf8 aq[4];
#pragma unroll
    for (int mi = 0; mi < 4; ++mi)
      aq[mi] = *(const bf8*)((const char*)sq + (mi * 16 + lm) * 528 + h * 128 + ks * 64 + lk * 16);
#pragma unroll
    for (int ni = 0; ni < 4; ++ni){
      bf8 bk = *(const bf8*)((const char*)skv + (h * 64 + ni * 16 + lm) * 144 + ks * 64 + lk * 16);
#pragma unroll
      for (int mi = 0; mi < 4; ++mi)
        acc[mi][ni] = __builtin_amdgcn_mfma_f32_16x16x32_bf16(aq[mi], bk, acc[mi][ni], 0, 0, 0);
    }
  }
#pragma unroll
  for (int mi = 0; mi < 4; ++mi)
#pragma unroll
    for (int ni = 0; ni < 4; ++ni){
      const int d = ni * 16 + lm, ch = h * 64 + d;
#pragma unroll
      for (int j = 0; j < 4; ++j){
        const int p = mi * 16 + lk * 4 + j;
        const float vf = bf2f(vg[(mrow + p) * 256 + ch]);
        const float gf = bf2f(gg[(mrow + p) * 256 + ch]);
        const float o = (acc[mi][ni][j] + vf) * sz[h * 64 + p] * gf;
        sq[p * 264 + ch] = f2bf(o);   // wave-local columns of sq
      }
    }
  __syncthreads();
#pragma unroll
  for (int it = 0; it < 8; ++it){
    const int q = it * 256 + t, p = q >> 5, c16 = (q & 31) * 8;
    *(bf8*)(y + (mrow + p) * 256 + c16) = *(const bf8*)((const char*)sq + p * 528 + c16 * 2);
  }
}

extern "C" void kernel_launch(void* const* d_in, const int* in_sizes, int n_in,
                              void* d_out, int out_size, void* d_ws, size_t ws_size,
                              hipStream_t stream){
  (void)in_sizes; (void)n_in; (void)out_size; (void)ws_size;
  const float* x   = (const float*)d_in[0];
  const float* wq1 = (const float*)d_in[1];
  const float* bq1 = (const float*)d_in[2];
  const float* wq2 = (const float*)d_in[3];
  const float* bq2 = (const float*)d_in[4];
  const float* wk1 = (const float*)d_in[5];
  const float* bk1 = (const float*)d_in[6];
  const float* wk2 = (const float*)d_in[7];
  const float* bk2 = (const float*)d_in[8];
  const float* wv  = (const float*)d_in[9];
  const float* bv  = (const float*)d_in[10];
  const float* wg  = (const float*)d_in[11];
  const float* bg  = (const float*)d_in[12];
  const float* wo  = (const float*)d_in[13];
  const float* bo  = (const float*)d_in[14];

  char* ws = (char*)d_ws;
  float* mu     = (float*)(ws + 0);
  float* rsig   = (float*)(ws + 8192);
  short* wb     = (short*)(ws + 16384);            // 7 x 65536 bf16
  float* kvpart = (float*)(ws + 933888);           // (b,h,s,c,d) partials, 4MB
  float* kspart = (float*)(ws + 5128192);          // 64KB
  short* kvT    = (short*)(ws + 5193728);          // 256KB
  float* ksum_s = (float*)(ws + 5455872);          // 8KB
  short* B0 = (short*)(ws + 8388608);              // xn -> y
  short* B1 = B0 + 33554432;                       // h1 -> v
  short* B2 = B1 + 33554432;                       // q
  short* B3 = B2 + 33554432;                       // k -> g

  k_wconv<<<448, 256, 0, stream>>>(wq1, wq2, wk1, wk2, wv, wg, wo, wb);
  k_stats<<<2048, 256, 0, stream>>>(x, mu, rsig);
  k_normt<<<dim3(256, 4, 8), 256, 0, stream>>>(x, mu, rsig, B0);
  k_gemm<1, 0><<<1024, 256, 0, stream>>>(B0, wb + 0 * 65536, bq1, B1);   // h1q = gelu
  k_gemm<2, 0><<<1024, 256, 0, stream>>>(B1, wb + 1 * 65536, bq2, B2);   // q = softplus
  k_gemm<1, 0><<<1024, 256, 0, stream>>>(B0, wb + 2 * 65536, bk1, B1);   // h1k
  k_gemm<2, 0><<<1024, 256, 0, stream>>>(B1, wb + 3 * 65536, bk2, B3);   // k
  k_gemm<1, 0><<<1024, 256, 0, stream>>>(B0, wb + 4 * 65536, bv, B1);    // v
  k_kv<<<dim3(8, 4, 8), 256, 0, stream>>>(B3, B1, kvpart, kspart);
  k_kvred<<<64, 256, 0, stream>>>(kvpart, kspart, kvT, ksum_s);
  k_gemm<1, 0><<<1024, 256, 0, stream>>>(B0, wb + 5 * 65536, bg, B3);    // g (k dead)
  k_attn<<<dim3(256, 8), 256, 0, stream>>>(B2, B1, B3, kvT, ksum_s, B0); // y (xn dead)
  k_gemm<0, 1><<<1024, 256, 0, stream>>>(B0, wb + 6 * 65536, bo, d_out); // final conv, fp32 CHW
}

// Round 3
// 467.875 us; speedup vs baseline: 2.1857x; 2.1857x over previous
//
#include <hip/hip_runtime.h>
#include <stdint.h>

typedef short bf8 __attribute__((ext_vector_type(8)));   // 8 bf16 in 4 VGPR
typedef short s4v __attribute__((ext_vector_type(4)));
typedef float f32x4 __attribute__((ext_vector_type(4)));

__device__ __forceinline__ short f2bf(float f){
  union { float f; unsigned u; } c; c.f = f;
  unsigned r = (c.u + 0x7fffu + ((c.u >> 16) & 1u)) >> 16;
  return (short)r;
}
__device__ __forceinline__ float bf2f(short s){
  union { unsigned u; float f; } c; c.u = ((unsigned)(unsigned short)s) << 16;
  return c.f;
}
__device__ __forceinline__ void gload16(const void* g, void* l){
  __builtin_amdgcn_global_load_lds((const __attribute__((address_space(1))) uint32_t*)g,
                                   (__attribute__((address_space(3))) uint32_t*)l, 16, 0, 0);
}
// Fast erf: Abramowitz-Stegun 7.1.26, |err| <= 1.5e-7, branchless ~14 VALU inst.
__device__ __forceinline__ float fast_erf(float x){
  const float s = fabsf(x);
  const float t = __builtin_amdgcn_rcpf(fmaf(0.3275911f, s, 1.0f));
  float p = fmaf(1.061405429f, t, -1.453152027f);
  p = fmaf(p, t, 1.421413741f);
  p = fmaf(p, t, -0.284496736f);
  p = fmaf(p, t, 0.254829592f);
  p = p * t;
  const float e = __expf(-s * s);
  return copysignf(fmaf(-p, e, 1.0f), x);
}
__device__ __forceinline__ float act_gelu(float x){
  return 0.5f * x * (1.0f + fast_erf(x * 0.70710678118654752f));
}
__device__ __forceinline__ float act_softplus(float x){
  const float e = __expf(-fabsf(x));
  return fmaxf(x, 0.0f) + __logf(1.0f + e);
}

// ---------------- instance-norm stats: one block per (b,c) row ----------------
__global__ __launch_bounds__(256) void k_stats(const float* __restrict__ x,
                                               float* __restrict__ mu, float* __restrict__ rsig){
  const int row = blockIdx.x;                 // 0..2047
  const float4* xr = (const float4*)(x + (size_t)row * 16384);
  float s1 = 0.f, s2 = 0.f;
  for (int i = threadIdx.x; i < 4096; i += 256){
    float4 v = xr[i];
    s1 += v.x + v.y + v.z + v.w;
    s2 += v.x*v.x + v.y*v.y + v.z*v.z + v.w*v.w;
  }
  __shared__ float a1[256], a2[256];
  a1[threadIdx.x] = s1; a2[threadIdx.x] = s2; __syncthreads();
  for (int s = 128; s > 0; s >>= 1){
    if (threadIdx.x < s){ a1[threadIdx.x] += a1[threadIdx.x+s]; a2[threadIdx.x] += a2[threadIdx.x+s]; }
    __syncthreads();
  }
  if (threadIdx.x == 0){
    float m = a1[0] * (1.0f/16384.0f);
    float v = a2[0] * (1.0f/16384.0f) - m*m;
    mu[row] = m; rsig[row] = rsqrtf(v + 1e-5f);
  }
}

// ------------- normalize + transpose: x (B,C,N) f32 -> xn (B,N,C) bf16 -------------
__global__ __launch_bounds__(256) void k_normt(const float* __restrict__ x, const float* __restrict__ mu,
                                               const float* __restrict__ rsig, short* __restrict__ xn){
  const int n0 = blockIdx.x * 64, c0 = blockIdx.y * 64, b = blockIdx.z;
  __shared__ short lt[64][68];
  const int t = threadIdx.x;
  const int nj = (t & 15) * 4, cb = t >> 4;
#pragma unroll
  for (int it = 0; it < 4; ++it){
    const int ci = cb + it * 16;
    const int row = b * 256 + c0 + ci;
    const float m = mu[row], rs = rsig[row];
    float4 v = *(const float4*)(x + (size_t)row * 16384 + n0 + nj);
    s4v o;
    o[0] = f2bf((v.x - m) * rs); o[1] = f2bf((v.y - m) * rs);
    o[2] = f2bf((v.z - m) * rs); o[3] = f2bf((v.w - m) * rs);
    *(s4v*)(&lt[ci][nj]) = o;
  }
  __syncthreads();
#pragma unroll
  for (int p = 0; p < 2; ++p){
    const int q = p * 256 + t;
    const int nl = q >> 3, c8 = (q & 7) * 8;
    bf8 o;
#pragma unroll
    for (int j = 0; j < 8; ++j) o[j] = lt[c8 + j][nl];
    *(bf8*)(xn + ((size_t)(b * 16384 + n0 + nl)) * 256 + c0 + c8) = o;
  }
}

// ------------- fp32->bf16 weight conversion (7 matrices of 256x256) -------------
__global__ __launch_bounds__(256) void k_wconv(const float* w0, const float* w1, const float* w2,
                                               const float* w3, const float* w4, const float* w5,
                                               const float* w6, short* __restrict__ wb){
  const int gid = blockIdx.x * 256 + threadIdx.x;
  const int mat = gid >> 14, r4 = gid & 16383;
  const float* srcs[7] = {w0, w1, w2, w3, w4, w5, w6};
  float4 v = *(const float4*)(srcs[mat] + (size_t)r4 * 4);
  s4v o; o[0] = f2bf(v.x); o[1] = f2bf(v.y); o[2] = f2bf(v.z); o[3] = f2bf(v.w);
  *(s4v*)(wb + (size_t)mat * 65536 + r4 * 4) = o;
}

// ---------------- GEMM: out[m][o] = act(sum_c A[m][c] * W[o][c] + bias[o]) ----------------
// 128x256 tile, 4 waves x (64x128). launch_bounds (256,2): proven config — VGPR 128 arch +
// AGPR accumulators, NO spill (round-2's (256,4) forced acc to scratch: 5x memory traffic).
template<int ACT, int OUTMODE>
__global__ __launch_bounds__(256, 2)
void k_gemm(const short* __restrict__ A, const short* __restrict__ W,
            const float* __restrict__ bias, void* __restrict__ outv){
  __shared__ short sm[12288];
  short* sA = sm;            // [128][32] bf16, 64B rows
  short* sB = sm + 4096;     // [256][32] bf16
  const int t = threadIdx.x, l = t & 63, w = t >> 6;
  const int wr = w >> 1, wc = w & 1;
  const int lm = l & 15, lk = l >> 4;
  const size_t m0 = (size_t)blockIdx.x * 128;
  const int swz = ((lk ^ ((lm >> 1) & 3)) << 4);
  f32x4 acc[4][8] = {};

  for (int ks = 0; ks < 8; ++ks){
    const int k0 = ks * 32;
#pragma unroll
    for (int p = 0; p < 2; ++p){
      const int q = p * 256 + t, r = q >> 2, kc = q & 3;
      gload16(A + (m0 + r) * 256 + k0 + ((kc ^ ((r >> 1) & 3)) << 3),
              (char*)sA + (p * 256 + w * 64) * 16);
    }
#pragma unroll
    for (int p = 0; p < 4; ++p){
      const int q = p * 256 + t, r = q >> 2, kc = q & 3;
      gload16(W + (size_t)r * 256 + k0 + ((kc ^ ((r >> 1) & 3)) << 3),
              (char*)sB + (p * 256 + w * 64) * 16);
    }
    __syncthreads();
    bf8 af[4], bfv[8];
#pragma unroll
    for (int mi = 0; mi < 4; ++mi)
      af[mi] = *(const bf8*)((const char*)sA + (wr * 64 + mi * 16 + lm) * 64 + swz);
#pragma unroll
    for (int ni = 0; ni < 8; ++ni)
      bfv[ni] = *(const bf8*)((const char*)sB + (wc * 128 + ni * 16 + lm) * 64 + swz);
#pragma unroll
    for (int mi = 0; mi < 4; ++mi)
#pragma unroll
      for (int ni = 0; ni < 8; ++ni)
        acc[mi][ni] = __builtin_amdgcn_mfma_f32_16x16x32_bf16(af[mi], bfv[ni], acc[mi][ni], 0, 0, 0);
    __syncthreads();
  }

  if constexpr (OUTMODE == 0){
    __shared__ short rp[32 * 264];
    short* outp = (short*)outv;
#pragma unroll
    for (int mi = 0; mi < 4; ++mi){
      __syncthreads();
      const int rloc = wr * 16 + lk * 4;
#pragma unroll
      for (int ni = 0; ni < 8; ++ni){
        const int o = wc * 128 + ni * 16 + lm;
        const float bi = bias[o];
#pragma unroll
        for (int j = 0; j < 4; ++j){
          float v = acc[mi][ni][j] + bi;
          if (ACT == 1) v = act_gelu(v);
          else if (ACT == 2) v = act_softplus(v);
          rp[(rloc + j) * 264 + o] = f2bf(v);
        }
      }
      __syncthreads();
#pragma unroll
      for (int it = 0; it < 4; ++it){
        const int q = it * 256 + t, rr = q >> 5, c = q & 31;
        const int gr = (rr >> 4) * 64 + mi * 16 + (rr & 15);
        *(bf8*)(outp + (m0 + gr) * 256 + c * 8) = *(const bf8*)(rp + rr * 264 + c * 8);
      }
    }
  } else {
    float* outp = (float*)outv;
    const size_t b = m0 >> 14;
    const int nb = (int)(m0 & 16383);
#pragma unroll
    for (int mi = 0; mi < 4; ++mi){
      const int np = nb + wr * 64 + mi * 16 + lk * 4;
#pragma unroll
      for (int ni = 0; ni < 8; ++ni){
        const int o = wc * 128 + ni * 16 + lm;
        const float bi = bias[o];
        float4 v;
        v.x = acc[mi][ni][0] + bi; v.y = acc[mi][ni][1] + bi;
        v.z = acc[mi][ni][2] + bi; v.w = acc[mi][ni][3] + bi;
        *(float4*)(outp + ((b * 256 + o) * 16384 + np)) = v;
      }
    }
  }
}

// -------- fused chain: out = softplus(gelu(xn*W1+b1)*W2+b2), 64-pixel tile --------
// h1 (64x256 bf16, 32KB) lives only in LDS with 16B-slot XOR layout slot^(row&7):
// pass-2 A-fragment reads (16 lanes = 16 rows, same slot) spread over 8 bank phases.
// LDS total 52KB -> 2-3 blocks/CU. Kills h1 global round-trip (128MB per chain).
__global__ __launch_bounds__(256, 2)
void k_chain(const short* __restrict__ A, const short* __restrict__ W1, const float* __restrict__ b1,
             const short* __restrict__ W2, const float* __restrict__ b2, short* __restrict__ out){
  __shared__ short sA[64 * 32];     // 4KB, [64][32], 64B rows, k-slot swizzled
  __shared__ short sB[256 * 32];    // 16KB
  __shared__ short h1[64 * 256];    // 32KB, 512B rows, slot-XOR layout
  const int t = threadIdx.x, l = t & 63, w = t >> 6;
  const int lm = l & 15, lk = l >> 4;
  const size_t m0 = (size_t)blockIdx.x * 64;
  const int swz = ((lk ^ ((lm >> 1) & 3)) << 4);
  f32x4 acc[4][4] = {};

  // ---- pass 1: h1 = gelu(A*W1 + b1) ----
  for (int ks = 0; ks < 8; ++ks){
    const int k0 = ks * 32;
    {
      const int r = t >> 2, kc = t & 3;
      gload16(A + (m0 + r) * 256 + k0 + ((kc ^ ((r >> 1) & 3)) << 3),
              (char*)sA + w * 1024);
    }
#pragma unroll
    for (int p = 0; p < 4; ++p){
      const int q = p * 256 + t, r = q >> 2, kc = q & 3;
      gload16(W1 + (size_t)r * 256 + k0 + ((kc ^ ((r >> 1) & 3)) << 3),
              (char*)sB + (p * 256 + w * 64) * 16);
    }
    __syncthreads();
    bf8 af[4], bfv[4];
#pragma unroll
    for (int mi = 0; mi < 4; ++mi)
      af[mi] = *(const bf8*)((const char*)sA + (mi * 16 + lm) * 64 + swz);
#pragma unroll
    for (int ni = 0; ni < 4; ++ni)
      bfv[ni] = *(const bf8*)((const char*)sB + (w * 64 + ni * 16 + lm) * 64 + swz);
#pragma unroll
    for (int mi = 0; mi < 4; ++mi)
#pragma unroll
      for (int ni = 0; ni < 4; ++ni)
        acc[mi][ni] = __builtin_amdgcn_mfma_f32_16x16x32_bf16(af[mi], bfv[ni], acc[mi][ni], 0, 0, 0);
    __syncthreads();
  }
#pragma unroll
  for (int mi = 0; mi < 4; ++mi)
#pragma unroll
    for (int ni = 0; ni < 4; ++ni){
      const int col = w * 64 + ni * 16 + lm;
      const float bi = b1[col];
#pragma unroll
      for (int j = 0; j < 4; ++j){
        const int row = mi * 16 + lk * 4 + j;
        const float v = act_gelu(acc[mi][ni][j] + bi);
        const int byte = row * 512 + ((((col >> 3) ^ (row & 7)) << 4) | ((col & 7) << 1));
        *(short*)((char*)h1 + byte) = f2bf(v);
      }
      acc[mi][ni] = (f32x4){0.f, 0.f, 0.f, 0.f};
    }
  __syncthreads();

  // ---- pass 2: out = softplus(h1*W2 + b2) ----
  for (int ks = 0; ks < 8; ++ks){
    const int k0 = ks * 32;
#pragma unroll
    for (int p = 0; p < 4; ++p){
      const int q = p * 256 + t, r = q >> 2, kc = q & 3;
      gload16(W2 + (size_t)r * 256 + k0 + ((kc ^ ((r >> 1) & 3)) << 3),
              (char*)sB + (p * 256 + w * 64) * 16);
    }
    __syncthreads();
    bf8 af[4], bfv[4];
#pragma unroll
    for (int mi = 0; mi < 4; ++mi){
      const int row = mi * 16 + lm;
      const int slot = (ks * 4 + lk) ^ (row & 7);
      af[mi] = *(const bf8*)((const char*)h1 + row * 512 + (slot << 4));
    }
#pragma unroll
    for (int ni = 0; ni < 4; ++ni)
      bfv[ni] = *(const bf8*)((const char*)sB + (w * 64 + ni * 16 + lm) * 64 + swz);
#pragma unroll
    for (int mi = 0; mi < 4; ++mi)
#pragma unroll
      for (int ni = 0; ni < 4; ++ni)
        acc[mi][ni] = __builtin_amdgcn_mfma_f32_16x16x32_bf16(af[mi], bfv[ni], acc[mi][ni], 0, 0, 0);
    __syncthreads();
  }
  // softplus + repack through h1 (dead now), then coalesced copy-out
#pragma unroll
  for (int mi = 0; mi < 4; ++mi)
#pragma unroll
    for (int ni = 0; ni < 4; ++ni){
      const int col = w * 64 + ni * 16 + lm;
      const float bi = b2[col];
#pragma unroll
      for (int j = 0; j < 4; ++j){
        const int row = mi * 16 + lk * 4 + j;
        const float v = act_softplus(acc[mi][ni][j] + bi);
        const int byte = row * 512 + ((((col >> 3) ^ (row & 7)) << 4) | ((col & 7) << 1));
        *(short*)((char*)h1 + byte) = f2bf(v);
      }
    }
  __syncthreads();
#pragma unroll
  for (int it = 0; it < 8; ++it){
    const int idx = it * 256 + t, r = idx >> 5, s = idx & 31;
    *(bf8*)(out + (m0 + r) * 256 + s * 8) =
        *(const bf8*)((const char*)h1 + r * 512 + (((s ^ (r & 7)) << 4)));
  }
}

// ---------- kv partials: kv[c][d] = sum_n K[c][n]*V[d][n], n split 8-way; + ksum ----------
__global__ __launch_bounds__(256) void k_kv(const short* __restrict__ kg, const short* __restrict__ vg,
                                            float* __restrict__ kvpart, float* __restrict__ kspart){
  const int s = blockIdx.x, h = blockIdx.y, b = blockIdx.z;
  __shared__ short sk[64 * 72], sv[64 * 72];
  __shared__ float pl[256][8];
  const int t = threadIdx.x, l = t & 63, w = t >> 6;
  const int lm = l & 15, lk = l >> 4;
  float ksp[8];
#pragma unroll
  for (int j = 0; j < 8; ++j) ksp[j] = 0.f;
  f32x4 acc[4] = {};
  const size_t rowbase = ((size_t)b * 16384 + s * 2048) * 256 + h * 64;

  for (int tt = 0; tt < 32; ++tt){
    __syncthreads();
#pragma unroll
    for (int p = 0; p < 2; ++p){
      const int q = p * 256 + t;
      const int nl = q >> 3, c8 = (q & 7) * 8;
      bf8 kvv = *(const bf8*)(kg + rowbase + (size_t)(tt * 64 + nl) * 256 + c8);
      bf8 vvv = *(const bf8*)(vg + rowbase + (size_t)(tt * 64 + nl) * 256 + c8);
#pragma unroll
      for (int j = 0; j < 8; ++j){
        sk[(c8 + j) * 72 + nl] = kvv[j];
        sv[(c8 + j) * 72 + nl] = vvv[j];
        ksp[j] += bf2f(kvv[j]);
      }
    }
    __syncthreads();
#pragma unroll
    for (int ks = 0; ks < 2; ++ks){
      bf8 ak = *(const bf8*)((const char*)sk + (w * 16 + lm) * 144 + ks * 64 + lk * 16);
#pragma unroll
      for (int ni = 0; ni < 4; ++ni){
        bf8 bv = *(const bf8*)((const char*)sv + (ni * 16 + lm) * 144 + ks * 64 + lk * 16);
        acc[ni] = __builtin_amdgcn_mfma_f32_16x16x32_bf16(ak, bv, acc[ni], 0, 0, 0);
      }
    }
  }
#pragma unroll
  for (int j = 0; j < 8; ++j) pl[t][j] = ksp[j];
  __syncthreads();
  const size_t slot = (size_t)(b * 4 + h) * 8 + s;
  if (t < 64){
    float sum = 0.f;
    const int g8 = t >> 3, j = t & 7;
    for (int m = 0; m < 32; ++m) sum += pl[m * 8 + g8][j];
    kspart[slot * 64 + t] = sum;
  }
  float* kvp = kvpart + slot * 4096;
#pragma unroll
  for (int ni = 0; ni < 4; ++ni)
#pragma unroll
    for (int j = 0; j < 4; ++j){
      const int c = w * 16 + lk * 4 + j, d = ni * 16 + lm;
      kvp[c * 64 + d] = acc[ni][j];
    }
}

// ---------- reduce partials -> kvT (b,h,d,c) bf16 (scale folded) + ksum fp32 ----------
__global__ __launch_bounds__(256) void k_kvred(const float* __restrict__ kvpart, const float* __restrict__ kspart,
                                               short* __restrict__ kvT, float* __restrict__ ksum_s){
  const int gid = blockIdx.x * 256 + threadIdx.x;
#pragma unroll
  for (int i = 0; i < 8; ++i){
    const int o = gid * 8 + i;
    const int bh = o >> 12, rem = o & 4095, d = rem >> 6, c = rem & 63;
    float sum = 0.f;
#pragma unroll
    for (int s = 0; s < 8; ++s) sum += kvpart[((size_t)bh * 8 + s) * 4096 + c * 64 + d];
    kvT[o] = f2bf(sum * 0.125f);
  }
  if (gid < 2048){
    float sum = 0.f;
#pragma unroll
    for (int s = 0; s < 8; ++s) sum += kspart[((size_t)(gid >> 6) * 8 + s) * 64 + (gid & 63)];
    ksum_s[gid] = sum * 0.125f;
  }
}

// ---------- attention finalize: y = ((q^T kv)*scale + v) * z * g, per 64-pixel tile ----------
__global__ __launch_bounds__(256, 2) void k_attn(const short* __restrict__ qg, const short* __restrict__ vg,
                                                 const short* __restrict__ gg, const short* __restrict__ kvT,
                                                 const float* __restrict__ ksum_s, short* __restrict__ y){
  const int n0 = blockIdx.x * 64, b = blockIdx.y;
  __shared__ short sq[64 * 264];
  __shared__ short skv[256 * 72];
  __shared__ float sz[256];
  __shared__ float sks[256];
  const int t = threadIdx.x, l = t & 63, w = t >> 6;
  const int lm = l & 15, lk = l >> 4;
  const size_t mrow = (size_t)b * 16384 + n0;

#pragma unroll
  for (int it = 0; it < 8; ++it){
    const int q = it * 256 + t, p = q >> 5, c16 = (q & 31) * 8;
    *(bf8*)((char*)sq + p * 528 + c16 * 2) = *(const bf8*)(qg + (mrow + p) * 256 + c16);
  }
  const short* kvb = kvT + (size_t)b * 16384;
#pragma unroll
  for (int it = 0; it < 8; ++it){
    const int q = it * 256 + t, r = q >> 3, c8 = (q & 7) * 8;
    *(bf8*)((char*)skv + r * 144 + c8 * 2) = *(const bf8*)(kvb + r * 64 + c8);
  }
  sks[t] = ksum_s[b * 256 + t];
  __syncthreads();

  {
    const int p = t & 63, h = t >> 6;
    float dot = 0.f;
#pragma unroll
    for (int cc = 0; cc < 8; ++cc){
      bf8 qv = *(const bf8*)((const char*)sq + p * 528 + (h * 64 + cc * 8) * 2);
#pragma unroll
      for (int j = 0; j < 8; ++j) dot += bf2f(qv[j]) * sks[h * 64 + cc * 8 + j];
    }
    sz[h * 64 + p] = 1.0f / (dot + 16384.0f);
  }

  const int h = w;
  f32x4 acc[4][4] = {};
#pragma unroll
  for (int ks = 0; ks < 2; ++ks){
    bf8 aq[4];
#pragma unroll
    for (int mi = 0; mi < 4; ++mi)
      aq[mi] = *(const bf8*)((const char*)sq + (mi * 16 + lm) * 528 + h * 128 + ks * 64 + lk * 16);
#pragma unroll
    for (int ni = 0; ni < 4; ++ni){
      bf8 bk = *(const bf8*)((const char*)skv + (h * 64 + ni * 16 + lm) * 144 + ks * 64 + lk * 16);
#pragma unroll
      for (int mi = 0; mi < 4; ++mi)
        acc[mi][ni] = __builtin_amdgcn_mfma_f32_16x16x32_bf16(aq[mi], bk, acc[mi][ni], 0, 0, 0);
    }
  }
#pragma unroll
  for (int mi = 0; mi < 4; ++mi)
#pragma unroll
    for (int ni = 0; ni < 4; ++ni){
      const int d = ni * 16 + lm, ch = h * 64 + d;
#pragma unroll
      for (int j = 0; j < 4; ++j){
        const int p = mi * 16 + lk * 4 + j;
        const float vf = bf2f(vg[(mrow + p) * 256 + ch]);
        const float gf = bf2f(gg[(mrow + p) * 256 + ch]);
        const float o = (acc[mi][ni][j] + vf) * sz[h * 64 + p] * gf;
        sq[p * 264 + ch] = f2bf(o);
      }
    }
  __syncthreads();
#pragma unroll
  for (int it = 0; it < 8; ++it){
    const int q = it * 256 + t, p = q >> 5, c16 = (q & 31) * 8;
    *(bf8*)(y + (mrow + p) * 256 + c16) = *(const bf8*)((const char*)sq + p * 528 + c16 * 2);
  }
}

extern "C" void kernel_launch(void* const* d_in, const int* in_sizes, int n_in,
                              void* d_out, int out_size, void* d_ws, size_t ws_size,
                              hipStream_t stream){
  (void)in_sizes; (void)n_in; (void)out_size; (void)ws_size;
  const float* x   = (const float*)d_in[0];
  const float* wq1 = (const float*)d_in[1];
  const float* bq1 = (const float*)d_in[2];
  const float* wq2 = (const float*)d_in[3];
  const float* bq2 = (const float*)d_in[4];
  const float* wk1 = (const float*)d_in[5];
  const float* bk1 = (const float*)d_in[6];
  const float* wk2 = (const float*)d_in[7];
  const float* bk2 = (const float*)d_in[8];
  const float* wv  = (const float*)d_in[9];
  const float* bv  = (const float*)d_in[10];
  const float* wg  = (const float*)d_in[11];
  const float* bg  = (const float*)d_in[12];
  const float* wo  = (const float*)d_in[13];
  const float* bo  = (const float*)d_in[14];

  char* ws = (char*)d_ws;
  float* mu     = (float*)(ws + 0);
  float* rsig   = (float*)(ws + 8192);
  short* wb     = (short*)(ws + 16384);            // 7 x 65536 bf16
  float* kvpart = (float*)(ws + 933888);           // (b,h,s,c,d) partials, 4MB
  float* kspart = (float*)(ws + 5128192);
  short* kvT    = (short*)(ws + 5193728);
  float* ksum_s = (float*)(ws + 5455872);
  short* B0 = (short*)(ws + 8388608);              // xn -> y
  short* B1 = B0 + 33554432;                       // v
  short* B2 = B1 + 33554432;                       // q
  short* B3 = B2 + 33554432;                       // k -> g

  k_wconv<<<448, 256, 0, stream>>>(wq1, wq2, wk1, wk2, wv, wg, wo, wb);
  k_stats<<<2048, 256, 0, stream>>>(x, mu, rsig);
  k_normt<<<dim3(256, 4, 8), 256, 0, stream>>>(x, mu, rsig, B0);
  k_chain<<<2048, 256, 0, stream>>>(B0, wb + 0 * 65536, bq1, wb + 1 * 65536, bq2, B2); // q
  k_chain<<<2048, 256, 0, stream>>>(B0, wb + 2 * 65536, bk1, wb + 3 * 65536, bk2, B3); // k
  k_gemm<1, 0><<<1024, 256, 0, stream>>>(B0, wb + 4 * 65536, bv, B1);    // v = gelu
  k_kv<<<dim3(8, 4, 8), 256, 0, stream>>>(B3, B1, kvpart, kspart);
  k_kvred<<<64, 256, 0, stream>>>(kvpart, kspart, kvT, ksum_s);
  k_gemm<1, 0><<<1024, 256, 0, stream>>>(B0, wb + 5 * 65536, bg, B3);    // g (k dead)
  k_attn<<<dim3(256, 8), 256, 0, stream>>>(B2, B1, B3, kvT, ksum_s, B0); // y (xn dead)
  k_gemm<0, 1><<<1024, 256, 0, stream>>>(B0, wb + 6 * 65536, bo, d_out); // final conv, fp32 CHW
}